// Round 4
// baseline (123.941 us; speedup 1.0000x reference)
//
#include <hip/hip_runtime.h>
#include <hip/hip_bf16.h>

#define B_  8
#define N_  100
#define T_  16
#define TP_ 15     // T-1 output steps (pred_steps == 1)
#define D_  4
#define H_  64
#define E_  9900   // N*(N-1)
#define RPB 8      // receivers per block
#define NG  13     // ceil(N/RPB)

typedef __attribute__((ext_vector_type(8))) short bf16x8;
typedef __attribute__((ext_vector_type(4))) float f32x4;

__device__ __forceinline__ unsigned short f2bf_u(float f) {
    return __builtin_bit_cast(unsigned short, __float2bfloat16(f));
}
__device__ __forceinline__ short f2bf_s(float f) {
    return (short)f2bf_u(f);
}
__device__ __forceinline__ float bflo(unsigned u) {   // low bf16 -> f32
    return __builtin_bit_cast(float, u << 16);
}
__device__ __forceinline__ float bfhi(unsigned u) {   // high bf16 -> f32
    return __builtin_bit_cast(float, u & 0xffff0000u);
}
__device__ __forceinline__ unsigned packbf(float a, float b) {
    return (unsigned)f2bf_u(a) | ((unsigned)f2bf_u(b) << 16);
}

// One block (4 waves) per (b, t, 8 receivers). All shared tables (u, epilogue
// weights, B-fragments) staged once per block; each wave independently handles
// one receiver per round. mf-major MFMA keeps acc at 16 VGPRs.
__global__ __launch_bounds__(256, 4)
void nri_v4(const float* __restrict__ x,        // (B,N,T,D)
            const float* __restrict__ rel,      // (B,E,2)
            const float* __restrict__ w1, const float* __restrict__ b1,   // k=1: (64,8),(64)
            const float* __restrict__ w2, const float* __restrict__ b2,   // k=1: (64,64),(64)
            const float* __restrict__ f1w, const float* __restrict__ f1b, // (64,68),(64)
            const float* __restrict__ f2w, const float* __restrict__ f2b, // (64,64),(64)
            const float* __restrict__ f3w, const float* __restrict__ f3b, // (4,64),(4)
            float* __restrict__ out)            // (B,N,TP,D)
{
    __shared__ unsigned short u_bf[N_][80];   // bf16 u, 160B rows (16B aligned)
    __shared__ unsigned ew1[34][65];          // f1w transposed bf16-pairs
    __shared__ unsigned ew2[32][65];          // f2w transposed bf16-pairs
    __shared__ unsigned ew3[32][5];           // f3w transposed bf16-pairs
    __shared__ float rt_w[4][112];
    __shared__ float v_w[4][H_];
    __shared__ float agg_w[4][H_];
    __shared__ float p1_w[4][H_];
    __shared__ float p2_w[4][H_];

    const int tid  = threadIdx.x;
    const int lane = tid & 63;
    const int w    = tid >> 6;
    const int bid  = blockIdx.x;
    const int g = bid % NG;
    const int t = (bid / NG) % TP_;
    const int b = bid / (NG * TP_);

    const float4 ws4 = *reinterpret_cast<const float4*>(w1 + lane * 8);
    const float4 wr4 = *reinterpret_cast<const float4*>(w1 + lane * 8 + 4);
    const float bv1  = b1[lane];
    const float bf1l = f1b[lane];
    const float bf2l = f2b[lane];
    const float bf3l = (lane < D_) ? f3b[lane] : 0.f;

    // ---- stage u[i][h] (bf16) for all 100 senders ----
    #pragma unroll 5
    for (int it = 0; it < 25; ++it) {
        const int r = it * 4 + w;
        const float4 xv = *reinterpret_cast<const float4*>(
            x + (((size_t)b * N_ + r) * T_ + t) * D_);
        const float u = ws4.x * xv.x + ws4.y * xv.y + ws4.z * xv.z + ws4.w * xv.w;
        u_bf[r][lane] = f2bf_u(u);
    }

    // ---- stage epilogue weights (transposed, bf16 pairs), coalesced ----
    for (int i2 = tid; i2 < 64 * 34; i2 += 256) {        // f1w: 64 rows x 34 pairs
        const int gg = i2 / 34, f2 = i2 - gg * 34;
        const float2 v2 = *reinterpret_cast<const float2*>(f1w + i2 * 2);
        ew1[f2][gg] = packbf(v2.x, v2.y);
    }
    for (int i2 = tid; i2 < 64 * 32; i2 += 256) {        // f2w: 64 x 32 pairs
        const int gg = i2 >> 5, f2 = i2 & 31;
        const float2 v2 = *reinterpret_cast<const float2*>(f2w + i2 * 2);
        ew2[f2][gg] = packbf(v2.x, v2.y);
    }
    if (tid < 128) {                                     // f3w: 4 x 32 pairs
        const int dd = tid >> 5, h2 = tid & 31;
        const float2 v2 = *reinterpret_cast<const float2*>(f3w + tid * 2);
        ew3[h2][dd] = packbf(v2.x, v2.y);
    }

    // ---- hoist W2^T B-fragments + b2 into registers ----
    const int col = lane & 15;
    const int kq  = (lane >> 4) * 8;
    bf16x8 bfr[2][4];
    #pragma unroll
    for (int s = 0; s < 2; ++s)
        #pragma unroll
        for (int nt = 0; nt < 4; ++nt) {
            const float* wp = w2 + (nt * 16 + col) * H_ + s * 32 + kq;
            const float4 wa = *reinterpret_cast<const float4*>(wp);
            const float4 wb = *reinterpret_cast<const float4*>(wp + 4);
            bf16x8 r;
            r[0] = f2bf_s(wa.x); r[1] = f2bf_s(wa.y);
            r[2] = f2bf_s(wa.z); r[3] = f2bf_s(wa.w);
            r[4] = f2bf_s(wb.x); r[5] = f2bf_s(wb.y);
            r[6] = f2bf_s(wb.z); r[7] = f2bf_s(wb.w);
            bfr[s][nt] = r;
        }
    float bb[4];
    #pragma unroll
    for (int nt = 0; nt < 4; ++nt) bb[nt] = b2[nt * 16 + col];

    __syncthreads();   // all block-shared tables ready; rest is wave-local

    #pragma unroll 1
    for (int rnd = 0; rnd < RPB / 4; ++rnd) {
        const int n = g * RPB + rnd * 4 + w;   // this wave's receiver
        if (n >= N_) continue;                 // wave-uniform

        // ---- early loads (latency hides under MFMA phase) ----
        const int ia  = lane + (lane >= n ? 1 : 0);
        const int eda = ia * (N_ - 1) + (n < ia ? n : n - 1);
        const float rva = rel[((size_t)b * E_ + eda) * 2 + 1];
        float rvb = 0.f;
        const int e2 = 64 + lane;
        if (e2 < N_ - 1) {
            const int ib  = e2 + (e2 >= n ? 1 : 0);
            const int edb = ib * (N_ - 1) + (n < ib ? n : n - 1);
            rvb = rel[((size_t)b * E_ + edb) * 2 + 1];
        }
        const float4 xr = *reinterpret_cast<const float4*>(
            x + (((size_t)b * N_ + n) * T_ + t) * D_);

        rt_w[w][lane] = rva;
        if (lane < 48) rt_w[w][64 + lane] = rvb;
        v_w[w][lane] = wr4.x * xr.x + wr4.y * xr.y + wr4.z * xr.z + wr4.w * xr.w
                       + bv1;
        __builtin_amdgcn_wave_barrier();

        // ---- h2 tile (M=112, N=64, K=64), mf-major; agg folded in ----
        float aggl[4] = {0.f, 0.f, 0.f, 0.f};
        #pragma unroll
        for (int mf = 0; mf < 7; ++mf) {
            const int e = mf * 16 + col;
            int i = e + (e >= n ? 1 : 0);
            if (i > N_ - 1) i = N_ - 1;        // pad rows read row 99 (rt=0)
            f32x4 acc[4] = {};
            #pragma unroll
            for (int s = 0; s < 2; ++s) {
                const int kk = s * 32 + kq;
                const uint4 ud = *reinterpret_cast<const uint4*>(&u_bf[i][kk]);
                const float4 v0 = *reinterpret_cast<const float4*>(&v_w[w][kk]);
                const float4 v1 = *reinterpret_cast<const float4*>(&v_w[w][kk + 4]);
                bf16x8 af;
                af[0] = f2bf_s(fmaxf(bflo(ud.x) + v0.x, 0.f));
                af[1] = f2bf_s(fmaxf(bfhi(ud.x) + v0.y, 0.f));
                af[2] = f2bf_s(fmaxf(bflo(ud.y) + v0.z, 0.f));
                af[3] = f2bf_s(fmaxf(bfhi(ud.y) + v0.w, 0.f));
                af[4] = f2bf_s(fmaxf(bflo(ud.z) + v1.x, 0.f));
                af[5] = f2bf_s(fmaxf(bfhi(ud.z) + v1.y, 0.f));
                af[6] = f2bf_s(fmaxf(bflo(ud.w) + v1.z, 0.f));
                af[7] = f2bf_s(fmaxf(bfhi(ud.w) + v1.w, 0.f));
                #pragma unroll
                for (int nt = 0; nt < 4; ++nt)
                    acc[nt] = __builtin_amdgcn_mfma_f32_16x16x32_bf16(
                        af, bfr[s][nt], acc[nt], 0, 0, 0);
            }
            const float4 rt4 = *reinterpret_cast<const float4*>(
                &rt_w[w][mf * 16 + (lane >> 4) * 4]);
            #pragma unroll
            for (int nt = 0; nt < 4; ++nt) {
                aggl[nt] += fmaxf(acc[nt][0] + bb[nt], 0.f) * rt4.x
                          + fmaxf(acc[nt][1] + bb[nt], 0.f) * rt4.y
                          + fmaxf(acc[nt][2] + bb[nt], 0.f) * rt4.z
                          + fmaxf(acc[nt][3] + bb[nt], 0.f) * rt4.w;
            }
        }
        #pragma unroll
        for (int nt = 0; nt < 4; ++nt) {
            float p = aggl[nt];
            p += __shfl_xor(p, 16, 64);
            p += __shfl_xor(p, 32, 64);
            if (lane < 16) agg_w[w][nt * 16 + col] = p;
        }
        __builtin_amdgcn_wave_barrier();

        // ---- p1 = relu(f1w @ [x, agg] + f1b), weights from LDS ----
        {
            const unsigned wp0 = ew1[0][lane], wp1 = ew1[1][lane];
            float a0 = bf1l + bflo(wp0) * xr.x + bfhi(wp0) * xr.y
                            + bflo(wp1) * xr.z + bfhi(wp1) * xr.w;
            float a1 = 0.f, a2 = 0.f, a3 = 0.f;
            #pragma unroll
            for (int m = 0; m < 32; m += 4) {
                const float4 agA = *reinterpret_cast<const float4*>(&agg_w[w][2 * m]);
                const float4 agB = *reinterpret_cast<const float4*>(&agg_w[w][2 * m + 4]);
                const unsigned q0 = ew1[2 + m][lane];
                const unsigned q1 = ew1[3 + m][lane];
                const unsigned q2 = ew1[4 + m][lane];
                const unsigned q3 = ew1[5 + m][lane];
                a0 += bflo(q0) * agA.x + bfhi(q0) * agA.y;
                a1 += bflo(q1) * agA.z + bfhi(q1) * agA.w;
                a2 += bflo(q2) * agB.x + bfhi(q2) * agB.y;
                a3 += bflo(q3) * agB.z + bfhi(q3) * agB.w;
            }
            p1_w[w][lane] = fmaxf((a0 + a1) + (a2 + a3), 0.f);
        }
        __builtin_amdgcn_wave_barrier();

        // ---- p2 = relu(f2w @ p1 + f2b) ----
        {
            float a0 = bf2l, a1 = 0.f, a2 = 0.f, a3 = 0.f;
            #pragma unroll
            for (int m = 0; m < 32; m += 4) {
                const float4 pA = *reinterpret_cast<const float4*>(&p1_w[w][2 * m]);
                const float4 pB = *reinterpret_cast<const float4*>(&p1_w[w][2 * m + 4]);
                const unsigned q0 = ew2[m][lane];
                const unsigned q1 = ew2[m + 1][lane];
                const unsigned q2 = ew2[m + 2][lane];
                const unsigned q3 = ew2[m + 3][lane];
                a0 += bflo(q0) * pA.x + bfhi(q0) * pA.y;
                a1 += bflo(q1) * pA.z + bfhi(q1) * pA.w;
                a2 += bflo(q2) * pB.x + bfhi(q2) * pB.y;
                a3 += bflo(q3) * pB.z + bfhi(q3) * pB.w;
            }
            p2_w[w][lane] = fmaxf((a0 + a1) + (a2 + a3), 0.f);
        }
        __builtin_amdgcn_wave_barrier();

        // ---- p3 (4x64) spread over all lanes + residual store ----
        {
            const int d   = lane & 3;
            const int seg = lane >> 2;
            const float4 pp = *reinterpret_cast<const float4*>(&p2_w[w][seg * 4]);
            const unsigned q0 = ew3[seg * 2][d];
            const unsigned q1 = ew3[seg * 2 + 1][d];
            float a = bflo(q0) * pp.x + bfhi(q0) * pp.y
                    + bflo(q1) * pp.z + bfhi(q1) * pp.w;
            a += __shfl_xor(a, 4, 64);
            a += __shfl_xor(a, 8, 64);
            a += __shfl_xor(a, 16, 64);
            a += __shfl_xor(a, 32, 64);
            if (lane < D_) {
                const float xv = (d == 0) ? xr.x : (d == 1) ? xr.y
                               : (d == 2) ? xr.z : xr.w;
                out[(((size_t)b * N_ + n) * TP_ + t) * D_ + d] = xv + bf3l + a;
            }
        }
    }
}

extern "C" void kernel_launch(void* const* d_in, const int* in_sizes, int n_in,
                              void* d_out, int out_size, void* d_ws, size_t ws_size,
                              hipStream_t stream) {
    const float* x   = (const float*)d_in[0];
    const float* rt  = (const float*)d_in[1];
    // d_in[2]=rel_rec, d_in[3]=rel_send: one-hot -> index arithmetic
    const float* w1  = (const float*)d_in[4] + 1 * H_ * 2 * D_;  // k=1 slice
    const float* b1  = (const float*)d_in[5] + 1 * H_;
    const float* w2  = (const float*)d_in[6] + 1 * H_ * H_;
    const float* b2  = (const float*)d_in[7] + 1 * H_;
    const float* f1w = (const float*)d_in[8];
    const float* f1b = (const float*)d_in[9];
    const float* f2w = (const float*)d_in[10];
    const float* f2b = (const float*)d_in[11];
    const float* f3w = (const float*)d_in[12];
    const float* f3b = (const float*)d_in[13];
    float* out = (float*)d_out;

    dim3 grid(B_ * TP_ * NG);
    nri_v4<<<grid, 256, 0, stream>>>(x, rt, w1, b1, w2, b2,
                                     f1w, f1b, f2w, f2b, f3w, f3b, out);
}

// Round 5
// 61.662 us; speedup vs baseline: 2.0100x; 2.0100x over previous
//
#include <hip/hip_runtime.h>
#include <hip/hip_bf16.h>

#define B_  8
#define N_  100
#define T_  16
#define TP_ 15     // T-1 output steps (pred_steps == 1)
#define D_  4
#define H_  64
#define E_  9900   // N*(N-1)
#define RPB 8      // receivers per block (kernel A)
#define NG  13     // ceil(N/RPB)
#define ROWS 12000 // B*TP*N

typedef __attribute__((ext_vector_type(8))) short bf16x8;
typedef __attribute__((ext_vector_type(4))) float f32x4;

__device__ __forceinline__ unsigned short f2bf_u(float f) {
    return __builtin_bit_cast(unsigned short, __float2bfloat16(f));
}
__device__ __forceinline__ short f2bf_s(float f) { return (short)f2bf_u(f); }
__device__ __forceinline__ float bflo(unsigned u) {
    return __builtin_bit_cast(float, u << 16);
}
__device__ __forceinline__ float bfhi(unsigned u) {
    return __builtin_bit_cast(float, u & 0xffff0000u);
}

// ============ Kernel A: message MLP + aggregation -> agg[ROWS][64] ==========
__global__ __launch_bounds__(256)
void nri_agg(const float* __restrict__ x,        // (B,N,T,D)
             const float* __restrict__ rel,      // (B,E,2)
             const float* __restrict__ w1, const float* __restrict__ b1,  // k=1
             const float* __restrict__ w2, const float* __restrict__ b2,  // k=1
             float* __restrict__ agg_out)        // (ROWS,64) in d_ws
{
    __shared__ unsigned short u_bf[N_][80];   // bf16 u rows (160B, 16B-aligned)
    __shared__ float rt_w[4][112];
    __shared__ float v_w[4][H_];

    const int tid  = threadIdx.x;
    const int lane = tid & 63;
    const int w    = tid >> 6;
    const int bid  = blockIdx.x;
    const int g = bid % NG;
    const int t = (bid / NG) % TP_;
    const int b = bid / (NG * TP_);

    const float4 ws4 = *reinterpret_cast<const float4*>(w1 + lane * 8);
    const float4 wr4 = *reinterpret_cast<const float4*>(w1 + lane * 8 + 4);
    const float bv1  = b1[lane];

    // stage u[i][h] = W1send @ x_i (bf16) for all 100 senders
    #pragma unroll 5
    for (int it = 0; it < 25; ++it) {
        const int r = it * 4 + w;
        const float4 xv = *reinterpret_cast<const float4*>(
            x + (((size_t)b * N_ + r) * T_ + t) * D_);
        u_bf[r][lane] = f2bf_u(ws4.x * xv.x + ws4.y * xv.y
                             + ws4.z * xv.z + ws4.w * xv.w);
    }

    // hoist W2^T B-fragments + b2 into registers (once per block)
    const int col = lane & 15;
    const int kq  = (lane >> 4) * 8;
    bf16x8 bfr[2][4];
    #pragma unroll
    for (int s = 0; s < 2; ++s)
        #pragma unroll
        for (int nt = 0; nt < 4; ++nt) {
            const float* wp = w2 + (nt * 16 + col) * H_ + s * 32 + kq;
            const float4 wa = *reinterpret_cast<const float4*>(wp);
            const float4 wb = *reinterpret_cast<const float4*>(wp + 4);
            bf16x8 r;
            r[0] = f2bf_s(wa.x); r[1] = f2bf_s(wa.y);
            r[2] = f2bf_s(wa.z); r[3] = f2bf_s(wa.w);
            r[4] = f2bf_s(wb.x); r[5] = f2bf_s(wb.y);
            r[6] = f2bf_s(wb.z); r[7] = f2bf_s(wb.w);
            bfr[s][nt] = r;
        }
    float bb[4];
    #pragma unroll
    for (int nt = 0; nt < 4; ++nt) bb[nt] = b2[nt * 16 + col];

    __syncthreads();   // u_bf ready; rest is wave-local

    #pragma unroll 1
    for (int rnd = 0; rnd < RPB / 4; ++rnd) {
        const int n = g * RPB + rnd * 4 + w;   // this wave's receiver
        if (n >= N_) continue;                 // wave-uniform

        // early loads
        const int ia  = lane + (lane >= n ? 1 : 0);
        const int eda = ia * (N_ - 1) + (n < ia ? n : n - 1);
        const float rva = rel[((size_t)b * E_ + eda) * 2 + 1];
        float rvb = 0.f;
        const int e2 = 64 + lane;
        if (e2 < N_ - 1) {
            const int ib  = e2 + (e2 >= n ? 1 : 0);
            const int edb = ib * (N_ - 1) + (n < ib ? n : n - 1);
            rvb = rel[((size_t)b * E_ + edb) * 2 + 1];
        }
        const float4 xr = *reinterpret_cast<const float4*>(
            x + (((size_t)b * N_ + n) * T_ + t) * D_);

        rt_w[w][lane] = rva;
        if (lane < 48) rt_w[w][64 + lane] = rvb;
        v_w[w][lane] = wr4.x * xr.x + wr4.y * xr.y + wr4.z * xr.z + wr4.w * xr.w
                       + bv1;
        __builtin_amdgcn_wave_barrier();

        // hoisted receiver-side vectors (loop-invariant across mf)
        const float4 v00 = *reinterpret_cast<const float4*>(&v_w[w][kq]);
        const float4 v01 = *reinterpret_cast<const float4*>(&v_w[w][kq + 4]);
        const float4 v10 = *reinterpret_cast<const float4*>(&v_w[w][32 + kq]);
        const float4 v11 = *reinterpret_cast<const float4*>(&v_w[w][32 + kq + 4]);

        // h2 tile (M=112 rows, N=64, K=64), mf-major, agg fold inline
        float aggl[4] = {0.f, 0.f, 0.f, 0.f};
        #pragma unroll
        for (int mf = 0; mf < 7; ++mf) {
            const int e = mf * 16 + col;
            int i = e + (e >= n ? 1 : 0);
            if (i > N_ - 1) i = N_ - 1;        // pad rows masked by rt=0
            f32x4 acc[4] = {};
            #pragma unroll
            for (int s = 0; s < 2; ++s) {
                const int kk = s * 32 + kq;
                const uint4 ud = *reinterpret_cast<const uint4*>(&u_bf[i][kk]);
                const float4 v0 = s ? v10 : v00;
                const float4 v1 = s ? v11 : v01;
                bf16x8 af;
                af[0] = f2bf_s(fmaxf(bflo(ud.x) + v0.x, 0.f));
                af[1] = f2bf_s(fmaxf(bfhi(ud.x) + v0.y, 0.f));
                af[2] = f2bf_s(fmaxf(bflo(ud.y) + v0.z, 0.f));
                af[3] = f2bf_s(fmaxf(bfhi(ud.y) + v0.w, 0.f));
                af[4] = f2bf_s(fmaxf(bflo(ud.z) + v1.x, 0.f));
                af[5] = f2bf_s(fmaxf(bfhi(ud.z) + v1.y, 0.f));
                af[6] = f2bf_s(fmaxf(bflo(ud.w) + v1.z, 0.f));
                af[7] = f2bf_s(fmaxf(bfhi(ud.w) + v1.w, 0.f));
                #pragma unroll
                for (int nt = 0; nt < 4; ++nt)
                    acc[nt] = __builtin_amdgcn_mfma_f32_16x16x32_bf16(
                        af, bfr[s][nt], acc[nt], 0, 0, 0);
            }
            const float4 rt4 = *reinterpret_cast<const float4*>(
                &rt_w[w][mf * 16 + (lane >> 4) * 4]);
            #pragma unroll
            for (int nt = 0; nt < 4; ++nt) {
                aggl[nt] += fmaxf(acc[nt][0] + bb[nt], 0.f) * rt4.x
                          + fmaxf(acc[nt][1] + bb[nt], 0.f) * rt4.y
                          + fmaxf(acc[nt][2] + bb[nt], 0.f) * rt4.z
                          + fmaxf(acc[nt][3] + bb[nt], 0.f) * rt4.w;
            }
        }
        const int row = (b * TP_ + t) * N_ + n;
        #pragma unroll
        for (int nt = 0; nt < 4; ++nt) {
            float p = aggl[nt];
            p += __shfl_xor(p, 16, 64);
            p += __shfl_xor(p, 32, 64);
            if (lane < 16)
                agg_out[(size_t)row * H_ + nt * 16 + col] = p;
        }
    }
}

// ============ Kernel B: out-MLP [x,agg] 68->64->64->4 + residual ============
// 750 blocks x 4 waves x 4 rows. Weights LDS-staged [g][f] stride-68;
// per-quad chunk rotation j' = (j + 4*(lane>>4)) % nch -> 2-way banks (free).
__global__ __launch_bounds__(256)
void nri_out(const float* __restrict__ x,        // (B,N,T,D)
             const float* __restrict__ agg_in,   // (ROWS,64) in d_ws
             const float* __restrict__ f1w, const float* __restrict__ f1b,
             const float* __restrict__ f2w, const float* __restrict__ f2b,
             const float* __restrict__ f3w, const float* __restrict__ f3b,
             float* __restrict__ out)            // (B,N,TP,D)
{
    __shared__ float ew1[64][68];   // f1w rows (stride 68, 16B-aligned)
    __shared__ float ew2[64][68];   // f2w rows (64 data + 4 pad)
    __shared__ float ew3[4][64];
    __shared__ float in_w[4][68];
    __shared__ float p1_w[4][H_];
    __shared__ float p2_w[4][H_];

    const int tid  = threadIdx.x;
    const int lane = tid & 63;
    const int w    = tid >> 6;

    for (int i = tid; i < 64 * 68; i += 256) {          // f1w copy
        const int gg = i / 68, f = i - gg * 68;
        ew1[gg][f] = f1w[i];
    }
    for (int i = tid; i < 64 * 64; i += 256) {          // f2w copy
        const int gg = i >> 6, f = i & 63;
        ew2[gg][f] = f2w[i];
    }
    for (int i = tid; i < 256; i += 256)                // f3w copy
        ew3[i >> 6][i & 63] = f3w[i];

    const float bf1 = f1b[lane];
    const float bf2 = f2b[lane];
    const float bf3 = (lane < D_) ? f3b[lane] : 0.f;
    const int rot = (lane >> 4) * 4;

    __syncthreads();

    #pragma unroll 1
    for (int rnd = 0; rnd < 4; ++rnd) {
        const int row = blockIdx.x * 16 + rnd * 4 + w;  // 750*16 = 12000 exact
        const int n  = row % N_;
        const int bt = row / N_;
        const int t  = bt % TP_;
        const int b  = bt / TP_;

        // stage in = [x(4) | agg(64)]
        if (lane == 0) {
            const float4 xv = *reinterpret_cast<const float4*>(
                x + (((size_t)b * N_ + n) * T_ + t) * D_);
            *reinterpret_cast<float4*>(&in_w[w][0]) = xv;
        } else if (lane <= 16) {
            const float4 av = *reinterpret_cast<const float4*>(
                agg_in + (size_t)row * H_ + (lane - 1) * 4);
            *reinterpret_cast<float4*>(&in_w[w][lane * 4]) = av;
        }
        __builtin_amdgcn_wave_barrier();

        // p1[g=lane] = relu(ew1[g] . in + b)
        float a0 = bf1, a1 = 0.f, a2 = 0.f, a3 = 0.f;
        #pragma unroll
        for (int j = 0; j < 17; j += 4) {
            #pragma unroll
            for (int q = 0; q < 4 && j + q < 17; ++q) {
                const int jj = j + q + rot >= 17 ? j + q + rot - 17 : j + q + rot;
                const float4 wv = *reinterpret_cast<const float4*>(&ew1[lane][jj * 4]);
                const float4 iv = *reinterpret_cast<const float4*>(&in_w[w][jj * 4]);
                float& acc = (q == 0) ? a0 : (q == 1) ? a1 : (q == 2) ? a2 : a3;
                acc = fmaf(wv.x, iv.x, acc);
                acc = fmaf(wv.y, iv.y, acc);
                acc = fmaf(wv.z, iv.z, acc);
                acc = fmaf(wv.w, iv.w, acc);
            }
        }
        p1_w[w][lane] = fmaxf((a0 + a1) + (a2 + a3), 0.f);
        __builtin_amdgcn_wave_barrier();

        // p2[g=lane] = relu(ew2[g] . p1 + b)
        a0 = bf2; a1 = 0.f; a2 = 0.f; a3 = 0.f;
        #pragma unroll
        for (int j = 0; j < 16; j += 4) {
            #pragma unroll
            for (int q = 0; q < 4; ++q) {
                const int jj = (j + q + rot) & 15;
                const float4 wv = *reinterpret_cast<const float4*>(&ew2[lane][jj * 4]);
                const float4 pv = *reinterpret_cast<const float4*>(&p1_w[w][jj * 4]);
                float& acc = (q == 0) ? a0 : (q == 1) ? a1 : (q == 2) ? a2 : a3;
                acc = fmaf(wv.x, pv.x, acc);
                acc = fmaf(wv.y, pv.y, acc);
                acc = fmaf(wv.z, pv.z, acc);
                acc = fmaf(wv.w, pv.w, acc);
            }
        }
        p2_w[w][lane] = fmaxf((a0 + a1) + (a2 + a3), 0.f);
        __builtin_amdgcn_wave_barrier();

        // p3[d] = ew3[d] . p2 ; out = x + b3 + p3
        {
            const int d   = lane & 3;
            const int seg = lane >> 2;
            const float4 wv = *reinterpret_cast<const float4*>(&ew3[d][seg * 4]);
            const float4 pv = *reinterpret_cast<const float4*>(&p2_w[w][seg * 4]);
            float s = wv.x * pv.x + wv.y * pv.y + wv.z * pv.z + wv.w * pv.w;
            s += __shfl_xor(s, 4, 64);
            s += __shfl_xor(s, 8, 64);
            s += __shfl_xor(s, 16, 64);
            s += __shfl_xor(s, 32, 64);
            if (lane < D_)
                out[(((size_t)b * N_ + n) * TP_ + t) * D_ + d] =
                    in_w[w][d] + bf3 + s;
        }
        __builtin_amdgcn_wave_barrier();
    }
}

extern "C" void kernel_launch(void* const* d_in, const int* in_sizes, int n_in,
                              void* d_out, int out_size, void* d_ws, size_t ws_size,
                              hipStream_t stream) {
    const float* x   = (const float*)d_in[0];
    const float* rt  = (const float*)d_in[1];
    // d_in[2]=rel_rec, d_in[3]=rel_send: one-hot -> index arithmetic
    const float* w1  = (const float*)d_in[4] + 1 * H_ * 2 * D_;  // k=1 slice
    const float* b1  = (const float*)d_in[5] + 1 * H_;
    const float* w2  = (const float*)d_in[6] + 1 * H_ * H_;
    const float* b2  = (const float*)d_in[7] + 1 * H_;
    const float* f1w = (const float*)d_in[8];
    const float* f1b = (const float*)d_in[9];
    const float* f2w = (const float*)d_in[10];
    const float* f2b = (const float*)d_in[11];
    const float* f3w = (const float*)d_in[12];
    const float* f3b = (const float*)d_in[13];
    float* out = (float*)d_out;
    float* agg = (float*)d_ws;   // needs ROWS*64*4 = 3,072,000 B of ws

    nri_agg<<<dim3(B_ * TP_ * NG), 256, 0, stream>>>(x, rt, w1, b1, w2, b2, agg);
    nri_out<<<dim3(ROWS / 16), 256, 0, stream>>>(x, agg, f1w, f1b, f2w, f2b,
                                                 f3w, f3b, out);
}